// Round 2
// baseline (1755.813 us; speedup 1.0000x reference)
//
#include <hip/hip_runtime.h>

typedef unsigned int u32;
typedef unsigned short u16;
typedef u16 u16x8 __attribute__((ext_vector_type(8)));
typedef u16 u16x4 __attribute__((ext_vector_type(4)));
typedef __bf16 bf16x8 __attribute__((ext_vector_type(8)));
typedef float f32x4 __attribute__((ext_vector_type(4)));
typedef float f32x2 __attribute__((ext_vector_type(2)));

#define B_SZ 32
#define S_SZ 128
#define T_SZ 127
#define DK 128
#define SKILL 256
#define RL 136 /* hS row length in elems: 128 + 8 pad (16B align kept, 2-way banks free) */

__device__ __forceinline__ float lof(u32 w) {
    union { u32 u; float f; } v; v.u = w << 16; return v.f;
}
__device__ __forceinline__ float hif(u32 w) {
    union { u32 u; float f; } v; v.u = w & 0xffff0000u; return v.f;
}
__device__ __forceinline__ u16 f2bf(float x) {
    union { float f; u32 u; } v; v.f = x;
    u32 r = v.u + 0x7fffu + ((v.u >> 16) & 1u);
    return (u16)(r >> 16);
}
__device__ __forceinline__ u32 pack2(float a, float b) {
    return (u32)f2bf(a) | ((u32)f2bf(b) << 16);
}
__device__ __forceinline__ float sigm(float x) {
    float e = __builtin_amdgcn_exp2f(-1.44269504f * x);
    return __builtin_amdgcn_rcpf(1.f + e);
}
__device__ __forceinline__ float tanh_f(float x) {
    float e = __builtin_amdgcn_exp2f(-2.88539008f * x);
    return 2.f * __builtin_amdgcn_rcpf(1.f + e) - 1.f;
}

// ---------------------------------------------------------------------------
// Kernel A: le[b,t,:] = W1 @ [ex | at | ans] + b1   for t in [0,127)
// ans is a broadcast scalar -> fold as ans * rowsum(W1[:,256:384])
// ---------------------------------------------------------------------------
__global__ __launch_bounds__(128) void k_le(
    const int* __restrict__ eid, const int* __restrict__ atime,
    const int* __restrict__ ansv, const float* __restrict__ ex_t,
    const float* __restrict__ at_t, const float* __restrict__ W1,
    const float* __restrict__ b1, float* __restrict__ le_ws)
{
    int t = blockIdx.x, bq = blockIdx.y, d = threadIdx.x;
    __shared__ float exS[128], atS[128];
    for (int bb = 0; bb < 4; ++bb) {
        int b = bq * 4 + bb;
        int e = eid[b * S_SZ + t];
        int a = atime[b * S_SZ + t];
        float av = (float)ansv[b * S_SZ + t];
        exS[d] = ex_t[e * DK + d];
        atS[d] = at_t[a * DK + d];
        __syncthreads();
        const float* wr = W1 + d * 384;
        float acc = b1[d];
        float wsum = 0.f;
        #pragma unroll 8
        for (int k4 = 0; k4 < 32; ++k4) {
            f32x4 w = *(const f32x4*)(wr + 4 * k4);
            acc += w[0] * exS[4 * k4] + w[1] * exS[4 * k4 + 1]
                 + w[2] * exS[4 * k4 + 2] + w[3] * exS[4 * k4 + 3];
        }
        #pragma unroll 8
        for (int k4 = 32; k4 < 64; ++k4) {
            f32x4 w = *(const f32x4*)(wr + 4 * k4);
            acc += w[0] * atS[4 * k4 - 128] + w[1] * atS[4 * k4 - 127]
                 + w[2] * atS[4 * k4 - 126] + w[3] * atS[4 * k4 - 125];
        }
        #pragma unroll 8
        for (int k4 = 64; k4 < 96; ++k4) {
            f32x4 w = *(const f32x4*)(wr + 4 * k4);
            wsum += w[0] + w[1] + w[2] + w[3];
        }
        acc += av * wsum;
        le_ws[(b * T_SZ + t) * DK + d] = acc;
        __syncthreads();
    }
}

// ---------------------------------------------------------------------------
// Kernel B: input-only parts of the gate pre-activations.
//   PRE_l[b,t] = bl + Wl[:,0:128]@le[t-1] + Wl[:,128:256]@itemb + Wl[:,256:384]@le[t]
//   PRE_g[b,t] = same with Wg
//   PRE_f[b,t] = bf + Wf[:,256:384]@itemb
// where itemb = it_table[interval_time[b,t+1]], le[-1] = 0.
// ---------------------------------------------------------------------------
__global__ __launch_bounds__(128) void k_pre(
    const int* __restrict__ itime, const float* __restrict__ it_t,
    const float* __restrict__ Wl, const float* __restrict__ blv,
    const float* __restrict__ Wg, const float* __restrict__ bgv,
    const float* __restrict__ Wf, const float* __restrict__ bfv,
    const float* __restrict__ le_ws,
    float* __restrict__ PRE_l, float* __restrict__ PRE_g, float* __restrict__ PRE_f)
{
    int t = blockIdx.x, bq = blockIdx.y, o = threadIdx.x;
    __shared__ float lp[128], lc[128], itS[128];
    for (int bb = 0; bb < 4; ++bb) {
        int b = bq * 4 + bb;
        int iv = itime[b * S_SZ + t + 1];
        itS[o] = it_t[iv * DK + o];
        lc[o] = le_ws[(b * T_SZ + t) * DK + o];
        lp[o] = (t == 0) ? 0.f : le_ws[(b * T_SZ + t - 1) * DK + o];
        __syncthreads();
        const float* wl = Wl + o * 512;
        const float* wg = Wg + o * 512;
        float al = blv[o], ag = bgv[o];
        #pragma unroll 8
        for (int k4 = 0; k4 < 32; ++k4) {
            f32x4 w  = *(const f32x4*)(wl + 4 * k4);
            f32x4 w2 = *(const f32x4*)(wg + 4 * k4);
            #pragma unroll
            for (int j = 0; j < 4; ++j) {
                float x = lp[4 * k4 + j];
                al += w[j] * x; ag += w2[j] * x;
            }
        }
        #pragma unroll 8
        for (int k4 = 32; k4 < 64; ++k4) {
            f32x4 w  = *(const f32x4*)(wl + 4 * k4);
            f32x4 w2 = *(const f32x4*)(wg + 4 * k4);
            #pragma unroll
            for (int j = 0; j < 4; ++j) {
                float x = itS[4 * k4 - 128 + j];
                al += w[j] * x; ag += w2[j] * x;
            }
        }
        #pragma unroll 8
        for (int k4 = 64; k4 < 96; ++k4) {
            f32x4 w  = *(const f32x4*)(wl + 4 * k4);
            f32x4 w2 = *(const f32x4*)(wg + 4 * k4);
            #pragma unroll
            for (int j = 0; j < 4; ++j) {
                float x = lc[4 * k4 - 256 + j];
                al += w[j] * x; ag += w2[j] * x;
            }
        }
        float af = bfv[o];
        const float* wf = Wf + o * 384 + 256;
        #pragma unroll 8
        for (int k4 = 0; k4 < 32; ++k4) {
            f32x4 w = *(const f32x4*)(wf + 4 * k4);
            af += w[0] * itS[4 * k4] + w[1] * itS[4 * k4 + 1]
                + w[2] * itS[4 * k4 + 2] + w[3] * itS[4 * k4 + 3];
        }
        size_t idx = (size_t)(b * T_SZ + t) * DK + o;
        PRE_l[idx] = al;
        PRE_g[idx] = ag;
        PRE_f[idx] = af;
        __syncthreads();
    }
}

// ---------------------------------------------------------------------------
// Kernel C: the sequential scan. One workgroup per batch element, 256 threads
// (4 waves, 2x2 tile split over d_out-half x skill-half).
//   per step: z_lg = wlgS @ h_tilde_pre + PRE  -> LG
//             c    = Wf2 @ LG + PRE_f
//             Zf   = Wf1 @ H^T  (MFMA, Wf1 A-frags persistent in VGPRs,
//                                H^T B-frags streamed from bf16 LDS mirror)
//             f = sigm(Zf + c);  h = kv_t*LG + f*h  (fp32 in registers)
//             h_tilde = sum_s kv_next[s]*h[s,:]  (butterfly + LDS atomics)
// ---------------------------------------------------------------------------
__global__ __launch_bounds__(256, 1) void k_main(
    const int* __restrict__ eid, const float* __restrict__ qmat,
    const float* __restrict__ Wl, const float* __restrict__ Wg,
    const float* __restrict__ Wf, const float* __restrict__ h0,
    const float* __restrict__ PRE_l, const float* __restrict__ PRE_g,
    const float* __restrict__ PRE_f, float* __restrict__ ht_ws)
{
    extern __shared__ char smem[];
    u32*   wlgS  = (u32*)smem;              // [64 kpairs][256 rows]  = 65536 B
    float* sh_z  = (float*)(smem + 65536);  // 256
    float* sh_LG = sh_z + 256;              // 128
    float* sh_c  = sh_LG + 128;             // 128
    float* sh_kt = sh_c + 128;              // 256
    float* sh_kn = sh_kt + 256;             // 256
    float* sh_ht = sh_kn + 256;             // 2 x 128 (double buffer)
    u16*   hS    = (u16*)(sh_ht + 256);     // [256][RL] bf16 = 69632 B

    const int b    = blockIdx.x;
    const int tid  = threadIdx.x;
    const int lane = tid & 63;
    const int wv   = tid >> 6;
    const int quad = lane >> 4;
    const int l4   = lane & 15;
    const int ih   = wv & 1;   // d_out half
    const int jh   = wv >> 1;  // skill half

    // ---- init: Wl4/Wg4 (h_tilde blocks, cols 384:512) -> LDS, bf16 pair-packed
    {
        const float* src = (tid < 128 ? Wl + tid * 512 : Wg + (tid - 128) * 512) + 384;
        #pragma unroll 8
        for (int k2 = 0; k2 < 64; ++k2)
            wlgS[k2 * 256 + tid] = pack2(src[2 * k2], src[2 * k2 + 1]);
    }
    // ---- init: Wf2 (LG block, cols 128:256) half-rows -> bf16 regs
    const int o2 = tid >> 1, hf = tid & 1;
    u16x8 wf2[8];
    #pragma unroll
    for (int sg = 0; sg < 8; ++sg) {
        const float* p = Wf + o2 * 384 + 128 + hf * 64 + sg * 8;
        #pragma unroll
        for (int j = 0; j < 8; ++j) wf2[sg][j] = f2bf(p[j]);
    }
    // ---- init: Wf1 (cols 0:128) A-frags -> bf16 regs (persistent all 127 steps)
    u16x8 afr[4][4];
    #pragma unroll
    for (int mt = 0; mt < 4; ++mt) {
        int m = 64 * ih + 16 * mt + l4;
        #pragma unroll
        for (int kt = 0; kt < 4; ++kt) {
            const float* p = Wf + m * 384 + kt * 32 + quad * 8;
            #pragma unroll
            for (int j = 0; j < 8; ++j) afr[mt][kt][j] = f2bf(p[j]);
        }
    }
    // ---- init: h0 -> fp32 regs (C-layout) + bf16 LDS mirror
    float hreg[4][8][4];
    #pragma unroll
    for (int mt = 0; mt < 4; ++mt) {
        int d0 = 64 * ih + 16 * mt + quad * 4;
        #pragma unroll
        for (int nt = 0; nt < 8; ++nt) {
            int s = 128 * jh + 16 * nt + l4;
            f32x4 hv = *(const f32x4*)(h0 + s * DK + d0);
            u16x4 pk;
            #pragma unroll
            for (int r = 0; r < 4; ++r) { hreg[mt][nt][r] = hv[r]; pk[r] = f2bf(hv[r]); }
            *(u16x4*)(hS + s * RL + d0) = pk;
        }
    }
    // ---- init: h_tilde_0 = kv[b,0] @ h0
    sh_kt[tid] = qmat[eid[b * S_SZ] * SKILL + tid];
    if (tid < 128) { sh_ht[tid] = 0.f; sh_ht[128 + tid] = 0.f; }
    __syncthreads();
    {
        float htp[16];
        #pragma unroll
        for (int v = 0; v < 16; ++v) htp[v] = 0.f;
        #pragma unroll
        for (int nt = 0; nt < 8; ++nt) {
            float kv = sh_kt[128 * jh + 16 * nt + l4];
            #pragma unroll
            for (int mt = 0; mt < 4; ++mt)
                #pragma unroll
                for (int r = 0; r < 4; ++r)
                    htp[mt * 4 + r] += kv * hreg[mt][nt][r];
        }
        #pragma unroll
        for (int mk = 1; mk <= 8; mk <<= 1)
            #pragma unroll
            for (int v = 0; v < 16; ++v)
                htp[v] += __shfl_xor(htp[v], mk, 64);
        float val = htp[0];
        #pragma unroll
        for (int v = 1; v < 16; ++v) val = (l4 == v) ? htp[v] : val;
        atomicAdd(&sh_ht[64 * ih + 16 * (l4 >> 2) + quad * 4 + (l4 & 3)], val);
    }
    __syncthreads();

    const int row = tid & 127;
    const int mat = tid >> 7;
    const float* PREzg = mat ? PRE_g : PRE_l;

    for (int t = 0; t < T_SZ; ++t) {
        const int p = t & 1;
        const float* htb = sh_ht + p * 128;
        // store h_tilde of previous step for the prediction epilogue
        if (t > 0 && tid < 128)
            ht_ws[(size_t)(b * T_SZ + (t - 1)) * DK + tid] = htb[tid];
        // phase 1: z = [Wl4;Wg4] @ h_tilde_pre + PRE ; tanh/sigm
        float z = 0.f;
        #pragma unroll 8
        for (int k2 = 0; k2 < 64; ++k2) {
            u32 w = wlgS[k2 * 256 + tid];
            f32x2 x = *(const f32x2*)(htb + 2 * k2);
            z += lof(w) * x[0] + hif(w) * x[1];
        }
        z += PREzg[(size_t)(b * T_SZ + t) * DK + row];
        sh_z[tid] = mat ? sigm(z) : tanh_f(z);
        // kv gathers for this step
        sh_kt[tid] = qmat[eid[b * S_SZ + t] * SKILL + tid];
        sh_kn[tid] = qmat[eid[b * S_SZ + t + 1] * SKILL + tid];
        __syncthreads();               // A
        if (tid < 128) {
            sh_LG[tid] = sh_z[128 + tid] * (sh_z[tid] + 1.f) * 0.5f;
            sh_ht[(1 - p) * 128 + tid] = 0.f;  // next write buffer
        }
        __syncthreads();               // B
        // phase 2: c = Wf2 @ LG + PRE_f
        {
            float pc = 0.f;
            #pragma unroll
            for (int sg = 0; sg < 8; ++sg) {
                u16x8 wvv = wf2[sg];
                #pragma unroll
                for (int jj = 0; jj < 8; ++jj) {
                    union { u32 u; float f; } cv; cv.u = ((u32)wvv[jj]) << 16;
                    pc += cv.f * sh_LG[hf * 64 + sg * 8 + jj];
                }
            }
            pc += __shfl_xor(pc, 1, 64);
            if (hf == 0)
                sh_c[o2] = pc + PRE_f[(size_t)(b * T_SZ + t) * DK + o2];
        }
        __syncthreads();               // C
        // phase 3: Zf^T = Wf1 @ H^T via MFMA 16x16x32 bf16
        f32x4 acc[4][8];
        #pragma unroll
        for (int mt = 0; mt < 4; ++mt)
            #pragma unroll
            for (int nt = 0; nt < 8; ++nt)
                acc[mt][nt] = (f32x4){0.f, 0.f, 0.f, 0.f};
        #pragma unroll
        for (int nt = 0; nt < 8; ++nt) {
            const u16* bp0 = hS + (128 * jh + 16 * nt + l4) * RL + quad * 8;
            u16x8 bfr[4];
            #pragma unroll
            for (int kt = 0; kt < 4; ++kt)
                bfr[kt] = *(const u16x8*)(bp0 + kt * 32);
            #pragma unroll
            for (int mt = 0; mt < 4; ++mt)
                #pragma unroll
                for (int kt = 0; kt < 4; ++kt)
                    acc[mt][nt] = __builtin_amdgcn_mfma_f32_16x16x32_bf16(
                        __builtin_bit_cast(bf16x8, afr[mt][kt]),
                        __builtin_bit_cast(bf16x8, bfr[kt]),
                        acc[mt][nt], 0, 0, 0);
        }
        __syncthreads();               // D (hS reads done before rewrites)
        // phase 4: gate, state update, h_tilde partials, LDS mirror rewrite
        float c4[4][4], lg4[4][4];
        #pragma unroll
        for (int mt = 0; mt < 4; ++mt) {
            int d0 = 64 * ih + 16 * mt + quad * 4;
            f32x4 cv = *(const f32x4*)(sh_c + d0);
            f32x4 lv = *(const f32x4*)(sh_LG + d0);
            #pragma unroll
            for (int r = 0; r < 4; ++r) { c4[mt][r] = cv[r]; lg4[mt][r] = lv[r]; }
        }
        float htp2[16];
        #pragma unroll
        for (int v = 0; v < 16; ++v) htp2[v] = 0.f;
        #pragma unroll
        for (int nt = 0; nt < 8; ++nt) {
            int s = 128 * jh + 16 * nt + l4;
            float kvt = sh_kt[s], kvn = sh_kn[s];
            #pragma unroll
            for (int mt = 0; mt < 4; ++mt) {
                int d0 = 64 * ih + 16 * mt + quad * 4;
                u16x4 pk;
                #pragma unroll
                for (int r = 0; r < 4; ++r) {
                    float zf = acc[mt][nt][r] + c4[mt][r];
                    float f  = sigm(zf);
                    float hn = kvt * lg4[mt][r] + f * hreg[mt][nt][r];
                    hreg[mt][nt][r] = hn;
                    htp2[mt * 4 + r] += kvn * hn;
                    pk[r] = f2bf(hn);
                }
                *(u16x4*)(hS + s * RL + d0) = pk;
            }
        }
        #pragma unroll
        for (int mk = 1; mk <= 8; mk <<= 1)
            #pragma unroll
            for (int v = 0; v < 16; ++v)
                htp2[v] += __shfl_xor(htp2[v], mk, 64);
        float val = htp2[0];
        #pragma unroll
        for (int v = 1; v < 16; ++v) val = (l4 == v) ? htp2[v] : val;
        atomicAdd(&sh_ht[(1 - p) * 128 + 64 * ih + 16 * (l4 >> 2) + quad * 4 + (l4 & 3)], val);
        __syncthreads();               // E
    }
    // final h_tilde (written at t=126 into buffer 1)
    if (tid < 128)
        ht_ws[(size_t)(b * T_SZ + (T_SZ - 1)) * DK + tid] = sh_ht[128 + tid];
}

// ---------------------------------------------------------------------------
// Kernel D: pred[b,t] = sigm(Wp @ [ex[b,t+1] | h_tilde[b,t]] + bp) -> f32 out
// ---------------------------------------------------------------------------
__global__ __launch_bounds__(128) void k_pred(
    const int* __restrict__ eid, const float* __restrict__ ex_t,
    const float* __restrict__ Wp, const float* __restrict__ bpv,
    const float* __restrict__ ht_ws, float* __restrict__ out)
{
    int t = blockIdx.x, bq = blockIdx.y, d = threadIdx.x;
    __shared__ float exS[128], htS[128];
    for (int bb = 0; bb < 4; ++bb) {
        int b = bq * 4 + bb;
        int e = eid[b * S_SZ + t + 1];
        exS[d] = ex_t[e * DK + d];
        htS[d] = ht_ws[(size_t)(b * T_SZ + t) * DK + d];
        __syncthreads();
        const float* wr = Wp + d * 256;
        float z = bpv[d];
        #pragma unroll 8
        for (int k4 = 0; k4 < 32; ++k4) {
            f32x4 w = *(const f32x4*)(wr + 4 * k4);
            z += w[0] * exS[4 * k4] + w[1] * exS[4 * k4 + 1]
               + w[2] * exS[4 * k4 + 2] + w[3] * exS[4 * k4 + 3];
        }
        #pragma unroll 8
        for (int k4 = 32; k4 < 64; ++k4) {
            f32x4 w = *(const f32x4*)(wr + 4 * k4);
            z += w[0] * htS[4 * k4 - 128] + w[1] * htS[4 * k4 - 127]
               + w[2] * htS[4 * k4 - 126] + w[3] * htS[4 * k4 - 125];
        }
        out[(size_t)(b * T_SZ + t) * DK + d] = sigm(z);
        __syncthreads();
    }
}

extern "C" void kernel_launch(void* const* d_in, const int* in_sizes, int n_in,
                              void* d_out, int out_size, void* d_ws, size_t ws_size,
                              hipStream_t stream) {
    const int* eid     = (const int*)d_in[0];
    const int* atime   = (const int*)d_in[1];
    const int* itime   = (const int*)d_in[2];
    const int* ansv    = (const int*)d_in[3];
    const float* qmat  = (const float*)d_in[4];
    const float* ex_t  = (const float*)d_in[5];
    const float* at_t  = (const float*)d_in[6];
    const float* it_t  = (const float*)d_in[7];
    const float* W1    = (const float*)d_in[8];
    const float* b1    = (const float*)d_in[9];
    const float* Wl    = (const float*)d_in[10];
    const float* blv   = (const float*)d_in[11];
    const float* Wg    = (const float*)d_in[12];
    const float* bgv   = (const float*)d_in[13];
    const float* Wf    = (const float*)d_in[14];
    const float* bfv   = (const float*)d_in[15];
    const float* Wp    = (const float*)d_in[16];
    const float* bpv   = (const float*)d_in[17];
    const float* h0    = (const float*)d_in[18];
    float* out = (float*)d_out;

    const size_t SZ = (size_t)B_SZ * T_SZ * DK;  // 520192 floats per array
    float* wsf   = (float*)d_ws;
    float* le_ws = wsf;
    float* PRE_l = wsf + SZ;
    float* PRE_g = wsf + 2 * SZ;
    float* PRE_f = wsf + 3 * SZ;
    float* ht_ws = wsf + 4 * SZ;

    // raise dynamic LDS cap for the scan kernel (140288 B, needs >64KB)
    hipFuncSetAttribute((const void*)k_main,
                        hipFuncAttributeMaxDynamicSharedMemorySize, 140288);

    dim3 g(T_SZ, 8);
    k_le  <<<g, 128, 0, stream>>>(eid, atime, ansv, ex_t, at_t, W1, b1, le_ws);
    k_pre <<<g, 128, 0, stream>>>(itime, it_t, Wl, blv, Wg, bgv, Wf, bfv,
                                  le_ws, PRE_l, PRE_g, PRE_f);
    k_main<<<dim3(B_SZ), 256, 140288, stream>>>(eid, qmat, Wl, Wg, Wf, h0,
                                                PRE_l, PRE_g, PRE_f, ht_ws);
    k_pred<<<g, 128, 0, stream>>>(eid, ex_t, Wp, bpv, ht_ws, out);
}

// Round 3
// 1333.342 us; speedup vs baseline: 1.3169x; 1.3169x over previous
//
#include <hip/hip_runtime.h>

typedef unsigned int u32;
typedef unsigned short u16;
typedef u16 u16x8 __attribute__((ext_vector_type(8)));
typedef u16 u16x4 __attribute__((ext_vector_type(4)));
typedef __bf16 bf16x8 __attribute__((ext_vector_type(8)));
typedef __bf16 bf16x4v __attribute__((ext_vector_type(4)));
typedef float f32x4 __attribute__((ext_vector_type(4)));
typedef float f32x2 __attribute__((ext_vector_type(2)));

#define B_SZ 32
#define S_SZ 128
#define T_SZ 127
#define DK 128
#define SKILL 256
#define RL 136   /* hS row pitch (u16): 128 + 8 pad -> dword stride 68 = 4*17 (odd*4), even bank spread */
#define PP 68    /* part row pitch (f32): 64 + 4 pad */

__device__ __forceinline__ u16x4 cvt4(f32x4 v) {
    return __builtin_bit_cast(u16x4, __builtin_convertvector(v, bf16x4v));
}
__device__ __forceinline__ u16x8 cvt8(f32x4 a, f32x4 b) {
    u16x4 x = cvt4(a), y = cvt4(b);
    u16x8 r;
    r[0]=x[0]; r[1]=x[1]; r[2]=x[2]; r[3]=x[3];
    r[4]=y[0]; r[5]=y[1]; r[6]=y[2]; r[7]=y[3];
    return r;
}
__device__ __forceinline__ u16 bfu(float x) {
    return __builtin_bit_cast(u16, (__bf16)x);
}
__device__ __forceinline__ float sigm(float x) {
    float e = __builtin_amdgcn_exp2f(-1.44269504f * x);
    return __builtin_amdgcn_rcpf(1.f + e);
}
__device__ __forceinline__ float tanh_f(float x) {
    float e = __builtin_amdgcn_exp2f(-2.88539008f * x);
    return 2.f * __builtin_amdgcn_rcpf(1.f + e) - 1.f;
}
__device__ __forceinline__ f32x4 mfma16(u16x8 a, u16x8 bb, f32x4 c) {
    return __builtin_amdgcn_mfma_f32_16x16x32_bf16(
        __builtin_bit_cast(bf16x8, a), __builtin_bit_cast(bf16x8, bb), c, 0, 0, 0);
}

// ---------------------------------------------------------------------------
// Kernel A: le[b,t,:] = W1 @ [ex | at | ans] + b1  (unchanged, proven)
// ---------------------------------------------------------------------------
__global__ __launch_bounds__(128) void k_le(
    const int* __restrict__ eid, const int* __restrict__ atime,
    const int* __restrict__ ansv, const float* __restrict__ ex_t,
    const float* __restrict__ at_t, const float* __restrict__ W1,
    const float* __restrict__ b1, float* __restrict__ le_ws)
{
    int t = blockIdx.x, bq = blockIdx.y, d = threadIdx.x;
    __shared__ float exS[128], atS[128];
    for (int bb = 0; bb < 4; ++bb) {
        int b = bq * 4 + bb;
        int e = eid[b * S_SZ + t];
        int a = atime[b * S_SZ + t];
        float av = (float)ansv[b * S_SZ + t];
        exS[d] = ex_t[e * DK + d];
        atS[d] = at_t[a * DK + d];
        __syncthreads();
        const float* wr = W1 + d * 384;
        float acc = b1[d];
        float wsum = 0.f;
        #pragma unroll 8
        for (int k4 = 0; k4 < 32; ++k4) {
            f32x4 w = *(const f32x4*)(wr + 4 * k4);
            acc += w[0] * exS[4 * k4] + w[1] * exS[4 * k4 + 1]
                 + w[2] * exS[4 * k4 + 2] + w[3] * exS[4 * k4 + 3];
        }
        #pragma unroll 8
        for (int k4 = 32; k4 < 64; ++k4) {
            f32x4 w = *(const f32x4*)(wr + 4 * k4);
            acc += w[0] * atS[4 * k4 - 128] + w[1] * atS[4 * k4 - 127]
                 + w[2] * atS[4 * k4 - 126] + w[3] * atS[4 * k4 - 125];
        }
        #pragma unroll 8
        for (int k4 = 64; k4 < 96; ++k4) {
            f32x4 w = *(const f32x4*)(wr + 4 * k4);
            wsum += w[0] + w[1] + w[2] + w[3];
        }
        acc += av * wsum;
        le_ws[(b * T_SZ + t) * DK + d] = acc;
        __syncthreads();
    }
}

// ---------------------------------------------------------------------------
// Kernel B: input-only gate pre-activations (unchanged, proven)
// ---------------------------------------------------------------------------
__global__ __launch_bounds__(128) void k_pre(
    const int* __restrict__ itime, const float* __restrict__ it_t,
    const float* __restrict__ Wl, const float* __restrict__ blv,
    const float* __restrict__ Wg, const float* __restrict__ bgv,
    const float* __restrict__ Wf, const float* __restrict__ bfv,
    const float* __restrict__ le_ws,
    float* __restrict__ PRE_l, float* __restrict__ PRE_g, float* __restrict__ PRE_f)
{
    int t = blockIdx.x, bq = blockIdx.y, o = threadIdx.x;
    __shared__ float lp[128], lc[128], itS[128];
    for (int bb = 0; bb < 4; ++bb) {
        int b = bq * 4 + bb;
        int iv = itime[b * S_SZ + t + 1];
        itS[o] = it_t[iv * DK + o];
        lc[o] = le_ws[(b * T_SZ + t) * DK + o];
        lp[o] = (t == 0) ? 0.f : le_ws[(b * T_SZ + t - 1) * DK + o];
        __syncthreads();
        const float* wl = Wl + o * 512;
        const float* wg = Wg + o * 512;
        float al = blv[o], ag = bgv[o];
        #pragma unroll 8
        for (int k4 = 0; k4 < 32; ++k4) {
            f32x4 w  = *(const f32x4*)(wl + 4 * k4);
            f32x4 w2 = *(const f32x4*)(wg + 4 * k4);
            #pragma unroll
            for (int j = 0; j < 4; ++j) {
                float x = lp[4 * k4 + j];
                al += w[j] * x; ag += w2[j] * x;
            }
        }
        #pragma unroll 8
        for (int k4 = 32; k4 < 64; ++k4) {
            f32x4 w  = *(const f32x4*)(wl + 4 * k4);
            f32x4 w2 = *(const f32x4*)(wg + 4 * k4);
            #pragma unroll
            for (int j = 0; j < 4; ++j) {
                float x = itS[4 * k4 - 128 + j];
                al += w[j] * x; ag += w2[j] * x;
            }
        }
        #pragma unroll 8
        for (int k4 = 64; k4 < 96; ++k4) {
            f32x4 w  = *(const f32x4*)(wl + 4 * k4);
            f32x4 w2 = *(const f32x4*)(wg + 4 * k4);
            #pragma unroll
            for (int j = 0; j < 4; ++j) {
                float x = lc[4 * k4 - 256 + j];
                al += w[j] * x; ag += w2[j] * x;
            }
        }
        float af = bfv[o];
        const float* wf = Wf + o * 384 + 256;
        #pragma unroll 8
        for (int k4 = 0; k4 < 32; ++k4) {
            f32x4 w = *(const f32x4*)(wf + 4 * k4);
            af += w[0] * itS[4 * k4] + w[1] * itS[4 * k4 + 1]
                + w[2] * itS[4 * k4 + 2] + w[3] * itS[4 * k4 + 3];
        }
        size_t idx = (size_t)(b * T_SZ + t) * DK + o;
        PRE_l[idx] = al;
        PRE_g[idx] = ag;
        PRE_f[idx] = af;
        __syncthreads();
    }
}

// ---------------------------------------------------------------------------
// Kernel C: sequential scan, 512 threads (8 waves, 2/SIMD).
//  per step: z = [Wl4;Wg4]@h~ (MFMA, row-interleaved so lanes hold zl/zg pairs)
//            LG in-register -> LDS (hi/lo bf16 + f32)
//            c = Wf2@LG (MFMA, hi/lo)
//            Zf = Wf1@H^T (MFMA, 2 nt-halves; half1 issued before barriers)
//            update h (fp32 regs), hS bf16 rewrite (wave-private rows)
//            h~ = kv_next^T H via f32 partial scatter + 512-thread reduce
// ---------------------------------------------------------------------------
__global__ __launch_bounds__(512, 1) void k_main(
    const int* __restrict__ eid, const float* __restrict__ qmat,
    const float* __restrict__ Wl, const float* __restrict__ Wg,
    const float* __restrict__ Wf, const float* __restrict__ h0,
    const float* __restrict__ PRE_l, const float* __restrict__ PRE_g,
    const float* __restrict__ PRE_f, float* __restrict__ ht_ws)
{
    extern __shared__ char smem[];
    u16*   hS   = (u16*)smem;                        // 256*136*2 = 69632
    float* part = (float*)(smem + 69632);            // 128*68*4 = 34816 -> 104448
    u16*   htbf = (u16*)(smem + 104448);             // hi[128], lo[128] = 512 -> 104960
    u16*   LGb  = (u16*)(smem + 104960);             // hi[128], lo[128] = 512 -> 105472
    float* LGf  = (float*)(smem + 105472);           // 512 -> 105984
    float* cS   = (float*)(smem + 105984);           // 512 -> 106496

    const int b    = blockIdx.x;
    const int tid  = threadIdx.x;
    const int w    = tid >> 6;
    const int lane = tid & 63;
    const int quad = lane >> 4;
    const int l4   = lane & 15;
    const int ih   = w & 1;    // d-half (Zf/update)
    const int jh   = w >> 1;   // s-quarter (Zf/update)

    // ---- persistent A-frags ----
    // Wf1 (Zf): m = 64ih+16mt+l4, k = 32kt+quad*8+j
    u16x8 afr[4][4];
    #pragma unroll
    for (int mt = 0; mt < 4; ++mt)
        #pragma unroll
        for (int kt = 0; kt < 4; ++kt) {
            const float* p = Wf + (64 * ih + 16 * mt + l4) * 384 + 32 * kt + quad * 8;
            afr[mt][kt] = cvt8(*(const f32x4*)p, *(const f32x4*)(p + 4));
        }
    // z stacked [Wl4;Wg4] row-interleaved: rho = 32w+16mt+l4 -> d=rho>>1, lg=rho&1
    u16x8 azf[2][4];
    #pragma unroll
    for (int mt = 0; mt < 2; ++mt)
        #pragma unroll
        for (int kt = 0; kt < 4; ++kt) {
            int d = 16 * w + 8 * mt + (l4 >> 1);
            const float* base = (l4 & 1) ? Wg : Wl;
            const float* p = base + d * 512 + 384 + 32 * kt + quad * 8;
            azf[mt][kt] = cvt8(*(const f32x4*)p, *(const f32x4*)(p + 4));
        }
    // Wf2 (c): m = 16w+l4, k = 32kt+quad*8+j
    u16x8 acf[4];
    #pragma unroll
    for (int kt = 0; kt < 4; ++kt) {
        const float* p = Wf + (16 * w + l4) * 384 + 128 + 32 * kt + quad * 8;
        acf[kt] = cvt8(*(const f32x4*)p, *(const f32x4*)(p + 4));
    }

    // ---- h0 -> fp32 regs (C-layout) + bf16 LDS mirror ----
    f32x4 hreg[4][4];   // [mt][nt]
    #pragma unroll
    for (int mt = 0; mt < 4; ++mt) {
        int d0 = 64 * ih + 16 * mt + quad * 4;
        #pragma unroll
        for (int nt = 0; nt < 4; ++nt) {
            int s = 64 * jh + 16 * nt + l4;
            f32x4 hv = *(const f32x4*)(h0 + s * DK + d0);
            hreg[mt][nt] = hv;
            *(u16x4*)(hS + s * RL + d0) = cvt4(hv);
        }
    }

    // ---- kv[t=0] into regs ----
    float kvt[4];
    {
        int e0 = eid[b * S_SZ];
        #pragma unroll
        for (int nt = 0; nt < 4; ++nt)
            kvt[nt] = qmat[e0 * SKILL + 64 * jh + 16 * nt + l4];
    }

    // ---- h~_0 = kv0^T @ h0 via scatter+reduce ----
    {
        float htp[16];
        #pragma unroll
        for (int v = 0; v < 16; ++v) htp[v] = 0.f;
        #pragma unroll
        for (int nt = 0; nt < 4; ++nt)
            #pragma unroll
            for (int mt = 0; mt < 4; ++mt)
                #pragma unroll
                for (int r = 0; r < 4; ++r)
                    htp[mt * 4 + r] += kvt[nt] * hreg[mt][nt][r];
        #pragma unroll
        for (int mt = 0; mt < 4; ++mt)
            #pragma unroll
            for (int r = 0; r < 4; ++r)
                part[(64 * ih + 16 * mt + quad * 4 + r) * PP + jh * 16 + l4] = htp[mt * 4 + r];
        __syncthreads();
        int d = tid >> 2, kq = tid & 3;
        const float* pp = part + d * PP + kq * 16;
        float v = 0.f;
        #pragma unroll
        for (int i4 = 0; i4 < 4; ++i4) {
            f32x4 x = *(const f32x4*)(pp + 4 * i4);
            v += x[0] + x[1] + x[2] + x[3];
        }
        v += __shfl_xor(v, 1, 64);
        v += __shfl_xor(v, 2, 64);
        if (kq == 0) {
            float hf = (float)(__bf16)v;
            htbf[d] = bfu(v);
            htbf[128 + d] = bfu(v - hf);
        }
        __syncthreads();
    }

    for (int t = 0; t < T_SZ; ++t) {
        const size_t tb = (size_t)(b * T_SZ + t) * DK;
        // ---- prefetch (global) ----
        int en = eid[b * S_SZ + t + 1];
        float kvn[4];
        #pragma unroll
        for (int nt = 0; nt < 4; ++nt)
            kvn[nt] = qmat[en * SKILL + 64 * jh + 16 * nt + l4];
        f32x2 pl[2], pg[2];
        #pragma unroll
        for (int mt = 0; mt < 2; ++mt) {
            int d0 = 16 * w + 8 * mt + 2 * quad;
            pl[mt] = *(const f32x2*)(PRE_l + tb + d0);
            pg[mt] = *(const f32x2*)(PRE_g + tb + d0);
        }
        f32x4 pf = *(const f32x4*)(PRE_f + tb + 16 * w + quad * 4);

        // ---- Zf half-1 (nt 0..1): B from hS (wave-private rows, no barrier) ----
        f32x4 accF[4][2];
        #pragma unroll
        for (int mt = 0; mt < 4; ++mt)
            #pragma unroll
            for (int n2 = 0; n2 < 2; ++n2)
                accF[mt][n2] = (f32x4){0.f, 0.f, 0.f, 0.f};
        #pragma unroll
        for (int n2 = 0; n2 < 2; ++n2) {
            const u16* bp = hS + (64 * jh + 16 * n2 + l4) * RL + quad * 8;
            u16x8 bfr[4];
            #pragma unroll
            for (int kt = 0; kt < 4; ++kt) bfr[kt] = *(const u16x8*)(bp + kt * 32);
            #pragma unroll
            for (int mt = 0; mt < 4; ++mt)
                #pragma unroll
                for (int kt = 0; kt < 4; ++kt)
                    accF[mt][n2] = mfma16(afr[mt][kt], bfr[kt], accF[mt][n2]);
        }

        // ---- z-MFMA: [Wl4;Wg4] @ h~ (hi + lo) ----
        f32x4 accZ[2];
        accZ[0] = (f32x4){0.f, 0.f, 0.f, 0.f};
        accZ[1] = (f32x4){0.f, 0.f, 0.f, 0.f};
        #pragma unroll
        for (int kt = 0; kt < 4; ++kt) {
            u16x8 bh = *(const u16x8*)(htbf + 32 * kt + quad * 8);
            u16x8 bl = *(const u16x8*)(htbf + 128 + 32 * kt + quad * 8);
            #pragma unroll
            for (int mt = 0; mt < 2; ++mt) {
                accZ[mt] = mfma16(azf[mt][kt], bh, accZ[mt]);
                accZ[mt] = mfma16(azf[mt][kt], bl, accZ[mt]);
            }
        }
        // ---- z epilogue -> LG (rows interleaved: r even = zl, r odd = zg) ----
        #pragma unroll
        for (int mt = 0; mt < 2; ++mt) {
            u32 hpack = 0, lpack = 0;
            f32x2 fpack;
            #pragma unroll
            for (int rp = 0; rp < 2; ++rp) {
                float zl = accZ[mt][2 * rp] + pl[mt][rp];
                float zg = accZ[mt][2 * rp + 1] + pg[mt][rp];
                float LGv = sigm(zg) * (tanh_f(zl) + 1.f) * 0.5f;
                float hif = (float)(__bf16)LGv;
                hpack |= ((u32)bfu(LGv)) << (16 * rp);
                lpack |= ((u32)bfu(LGv - hif)) << (16 * rp);
                fpack[rp] = LGv;
            }
            if (l4 == 0) {
                int d0 = 16 * w + 8 * mt + 2 * quad;
                *(u32*)(LGb + d0) = hpack;
                *(u32*)(LGb + 128 + d0) = lpack;
                *(f32x2*)(LGf + d0) = fpack;
            }
        }
        __syncthreads();   // B: LG ready

        // ---- c-MFMA: Wf2 @ LG (hi+lo) ----
        {
            f32x4 accC = (f32x4){0.f, 0.f, 0.f, 0.f};
            #pragma unroll
            for (int kt = 0; kt < 4; ++kt) {
                u16x8 bh = *(const u16x8*)(LGb + 32 * kt + quad * 8);
                u16x8 bl = *(const u16x8*)(LGb + 128 + 32 * kt + quad * 8);
                accC = mfma16(acf[kt], bh, accC);
                accC = mfma16(acf[kt], bl, accC);
            }
            accC += pf;
            if (l4 == 0) *(f32x4*)(cS + 16 * w + quad * 4) = accC;
        }
        __syncthreads();   // C: c ready

        // ---- update half-1 (nt 0..1) ----
        float htp[16];
        #pragma unroll
        for (int v = 0; v < 16; ++v) htp[v] = 0.f;
        #pragma unroll
        for (int mt = 0; mt < 4; ++mt) {
            int d0 = 64 * ih + 16 * mt + quad * 4;
            f32x4 lg = *(const f32x4*)(LGf + d0);
            f32x4 cc = *(const f32x4*)(cS + d0);
            #pragma unroll
            for (int n2 = 0; n2 < 2; ++n2) {
                int s = 64 * jh + 16 * n2 + l4;
                f32x4 hv;
                #pragma unroll
                for (int r = 0; r < 4; ++r) {
                    float f = sigm(accF[mt][n2][r] + cc[r]);
                    float hn = kvt[n2] * lg[r] + f * hreg[mt][n2][r];
                    hreg[mt][n2] [r] = hn;
                    htp[mt * 4 + r] += kvn[n2] * hn;
                    hv[r] = hn;
                }
                *(u16x4*)(hS + s * RL + d0) = cvt4(hv);
            }
        }
        // ---- Zf half-2 (nt 2..3, rows untouched by half-1) + update ----
        #pragma unroll
        for (int mt = 0; mt < 4; ++mt)
            #pragma unroll
            for (int n2 = 0; n2 < 2; ++n2)
                accF[mt][n2] = (f32x4){0.f, 0.f, 0.f, 0.f};
        #pragma unroll
        for (int n2 = 0; n2 < 2; ++n2) {
            const u16* bp = hS + (64 * jh + 16 * (2 + n2) + l4) * RL + quad * 8;
            u16x8 bfr[4];
            #pragma unroll
            for (int kt = 0; kt < 4; ++kt) bfr[kt] = *(const u16x8*)(bp + kt * 32);
            #pragma unroll
            for (int mt = 0; mt < 4; ++mt)
                #pragma unroll
                for (int kt = 0; kt < 4; ++kt)
                    accF[mt][n2] = mfma16(afr[mt][kt], bfr[kt], accF[mt][n2]);
        }
        #pragma unroll
        for (int mt = 0; mt < 4; ++mt) {
            int d0 = 64 * ih + 16 * mt + quad * 4;
            f32x4 lg = *(const f32x4*)(LGf + d0);
            f32x4 cc = *(const f32x4*)(cS + d0);
            #pragma unroll
            for (int n2 = 0; n2 < 2; ++n2) {
                int nt = 2 + n2;
                int s = 64 * jh + 16 * nt + l4;
                f32x4 hv;
                #pragma unroll
                for (int r = 0; r < 4; ++r) {
                    float f = sigm(accF[mt][n2][r] + cc[r]);
                    float hn = kvt[nt] * lg[r] + f * hreg[mt][nt][r];
                    hreg[mt][nt][r] = hn;
                    htp[mt * 4 + r] += kvn[nt] * hn;
                    hv[r] = hn;
                }
                *(u16x4*)(hS + s * RL + d0) = cvt4(hv);
            }
        }
        // ---- h~ partial scatter ----
        #pragma unroll
        for (int mt = 0; mt < 4; ++mt)
            #pragma unroll
            for (int r = 0; r < 4; ++r)
                part[(64 * ih + 16 * mt + quad * 4 + r) * PP + jh * 16 + l4] = htp[mt * 4 + r];
        #pragma unroll
        for (int nt = 0; nt < 4; ++nt) kvt[nt] = kvn[nt];
        __syncthreads();   // E: partials ready
        // ---- reduce -> h~ (hi/lo bf16) + ht_ws ----
        {
            int d = tid >> 2, kq = tid & 3;
            const float* pp = part + d * PP + kq * 16;
            float v = 0.f;
            #pragma unroll
            for (int i4 = 0; i4 < 4; ++i4) {
                f32x4 x = *(const f32x4*)(pp + 4 * i4);
                v += x[0] + x[1] + x[2] + x[3];
            }
            v += __shfl_xor(v, 1, 64);
            v += __shfl_xor(v, 2, 64);
            if (kq == 0) {
                float hf = (float)(__bf16)v;
                htbf[d] = bfu(v);
                htbf[128 + d] = bfu(v - hf);
                ht_ws[tb + d] = v;
            }
        }
        __syncthreads();   // TOP: h~ ready, part free
    }
}

// ---------------------------------------------------------------------------
// Kernel D: pred (unchanged, proven)
// ---------------------------------------------------------------------------
__global__ __launch_bounds__(128) void k_pred(
    const int* __restrict__ eid, const float* __restrict__ ex_t,
    const float* __restrict__ Wp, const float* __restrict__ bpv,
    const float* __restrict__ ht_ws, float* __restrict__ out)
{
    int t = blockIdx.x, bq = blockIdx.y, d = threadIdx.x;
    __shared__ float exS[128], htS[128];
    for (int bb = 0; bb < 4; ++bb) {
        int b = bq * 4 + bb;
        int e = eid[b * S_SZ + t + 1];
        exS[d] = ex_t[e * DK + d];
        htS[d] = ht_ws[(size_t)(b * T_SZ + t) * DK + d];
        __syncthreads();
        const float* wr = Wp + d * 256;
        float z = bpv[d];
        #pragma unroll 8
        for (int k4 = 0; k4 < 32; ++k4) {
            f32x4 w = *(const f32x4*)(wr + 4 * k4);
            z += w[0] * exS[4 * k4] + w[1] * exS[4 * k4 + 1]
               + w[2] * exS[4 * k4 + 2] + w[3] * exS[4 * k4 + 3];
        }
        #pragma unroll 8
        for (int k4 = 32; k4 < 64; ++k4) {
            f32x4 w = *(const f32x4*)(wr + 4 * k4);
            z += w[0] * htS[4 * k4 - 128] + w[1] * htS[4 * k4 - 127]
               + w[2] * htS[4 * k4 - 126] + w[3] * htS[4 * k4 - 125];
        }
        out[(size_t)(b * T_SZ + t) * DK + d] = sigm(z);
        __syncthreads();
    }
}

extern "C" void kernel_launch(void* const* d_in, const int* in_sizes, int n_in,
                              void* d_out, int out_size, void* d_ws, size_t ws_size,
                              hipStream_t stream) {
    const int* eid     = (const int*)d_in[0];
    const int* atime   = (const int*)d_in[1];
    const int* itime   = (const int*)d_in[2];
    const int* ansv    = (const int*)d_in[3];
    const float* qmat  = (const float*)d_in[4];
    const float* ex_t  = (const float*)d_in[5];
    const float* at_t  = (const float*)d_in[6];
    const float* it_t  = (const float*)d_in[7];
    const float* W1    = (const float*)d_in[8];
    const float* b1    = (const float*)d_in[9];
    const float* Wl    = (const float*)d_in[10];
    const float* blv   = (const float*)d_in[11];
    const float* Wg    = (const float*)d_in[12];
    const float* bgv   = (const float*)d_in[13];
    const float* Wf    = (const float*)d_in[14];
    const float* bfv   = (const float*)d_in[15];
    const float* Wp    = (const float*)d_in[16];
    const float* bpv   = (const float*)d_in[17];
    const float* h0    = (const float*)d_in[18];
    float* out = (float*)d_out;

    const size_t SZ = (size_t)B_SZ * T_SZ * DK;
    float* wsf   = (float*)d_ws;
    float* le_ws = wsf;
    float* PRE_l = wsf + SZ;
    float* PRE_g = wsf + 2 * SZ;
    float* PRE_f = wsf + 3 * SZ;
    float* ht_ws = wsf + 4 * SZ;

    hipFuncSetAttribute((const void*)k_main,
                        hipFuncAttributeMaxDynamicSharedMemorySize, 106496);

    dim3 g(T_SZ, 8);
    k_le  <<<g, 128, 0, stream>>>(eid, atime, ansv, ex_t, at_t, W1, b1, le_ws);
    k_pre <<<g, 128, 0, stream>>>(itime, it_t, Wl, blv, Wg, bgv, Wf, bfv,
                                  le_ws, PRE_l, PRE_g, PRE_f);
    k_main<<<dim3(B_SZ), 512, 106496, stream>>>(eid, qmat, Wl, Wg, Wf, h0,
                                                PRE_l, PRE_g, PRE_f, ht_ws);
    k_pred<<<g, 128, 0, stream>>>(eid, ex_t, Wp, bpv, ht_ws, out);
}